// Round 2
// baseline (1026.171 us; speedup 1.0000x reference)
//
#include <hip/hip_runtime.h>

#define NB 2048
#define HDM 64
#define NLAY 5
#define NBLK 256

typedef __bf16 bf16x8 __attribute__((ext_vector_type(8)));
typedef float v4f __attribute__((ext_vector_type(4)));

__device__ __forceinline__ float sigmoidf_(float x){ return 1.f/(1.f+__expf(-x)); }
__device__ __forceinline__ float tanhfast_(float x){
  x = fminf(fmaxf(x, -15.f), 15.f);
  float e = __expf(2.f*x);
  return (e-1.f)/(e+1.f);
}
__device__ __forceinline__ unsigned short f2b_rne(float f){
  unsigned u = __float_as_uint(f);
  unsigned r = u + 0x7FFFu + ((u>>16)&1u);
  return (unsigned short)(r>>16);
}
__device__ __forceinline__ unsigned pk2(float a, float b){
  unsigned ua = (__float_as_uint(a) + 0x8000u) >> 16;
  unsigned ub = (__float_as_uint(b) + 0x8000u) & 0xFFFF0000u;
  return ua | ub;
}

// ============================ fused kernel (plain launch, software grid barrier) ============
// 256 blocks x 256 threads, __launch_bounds__(256,2) -> capacity >= 512 blocks on 256 CUs
// (2x co-residency margin; even at 1 block/CU all 256 blocks are resident simultaneously).

struct KArgs {
  const float *x, *tt, *freqs, *fc1W, *fc1b, *fc2W, *fc2b, *nodeW, *nodeb,
              *tprojW, *tprojb, *tcatW, *tcatb, *penb, *pelW, *pelb, *catW, *catb,
              *convWg, *gruWih, *grubih, *gruWhh, *grubhh, *Wqkv, *bqkv, *Wo, *bo,
              *bng, *bnb, *W1, *b1, *W2, *b2, *outW, *outb;
  float *htime, *hbuf, *gh, *s1, *s2, *smlp, *o_out, *hsum, *bnacc, *h0p, *out;
  unsigned short *Qb, *Kb, *Vt;
  unsigned *bar;
};

union SMem {
  struct { float xs[16*260]; float tb0[256]; float tb1[256]; } pre;             // 18688 B
  struct { float sa[256]; float sb[256]; float cvec[64]; } as;                  // 2304 B
  struct { float sa[512]; } a;                                                  // 2048 B
  struct { unsigned short Pl[4*640]; float Os[4*272]; float ms[64]; float ls[64]; } at; // 9984 B
  struct { float sa[512]; float os[512]; float smv[64]; float sgi[192]; float Sb1[512]; float Sb2[512]; } b2; // 9216 B
  struct { float sa[512]; float sh[8*128]; float S2[512]; } c;                  // 8192 B
  struct { float hsT[64*20]; } o;                                               // 5120 B
};

// Slot-per-barrier grid sync. Slots zeroed each launch by the in-graph memset.
// All NBLK blocks are co-resident (capacity 2x), so arrival is guaranteed.
// Watchdog: if something impossible happens, fail loud (wrong data) instead of hanging.
__device__ __forceinline__ void gsync(unsigned* slotp){
  __syncthreads();
  if (threadIdx.x == 0){
    __threadfence();   // make this block's writes visible device-wide
    __hip_atomic_fetch_add(slotp, 1u, __ATOMIC_RELEASE, __HIP_MEMORY_SCOPE_AGENT);
    unsigned spins = 0u;
    while (__hip_atomic_load(slotp, __ATOMIC_ACQUIRE, __HIP_MEMORY_SCOPE_AGENT) < (unsigned)NBLK){
      __builtin_amdgcn_s_sleep(2);
      if (++spins > 4000000u) break;
    }
    __threadfence();   // invalidate stale cache lines before re-reading shared data
  }
  __syncthreads();
}

__global__ __launch_bounds__(256, 2) void k_fused(KArgs A)
{
  __shared__ SMem sm;
  const int t = threadIdx.x;
  const int b = blockIdx.x;
  int slot = 0;

  // ================= Phase P: zero accumulators + time-embedding + GEMM1 =================
  if (b == 0){
    for (int i = t; i < 320 + 1920; i += 256) A.hsum[i] = 0.f;   // hsum + bnacc contiguous
  }
  {
    // time embedding: 8 rows/block, 4 rows per pass
    const int r = t>>6, c = t&63;
    for (int pass=0; pass<2; ++pass){
      if (pass) __syncthreads();
      const int row = b*8 + pass*4 + r;
      const float tv = A.tt[row];
      float te[16];
      #pragma unroll
      for (int j=0;j<8;++j){
        float sv, cv;
        __sincosf(6.28318530717958647692f*tv*A.freqs[j], &sv, &cv);
        te[j]=sv; te[j+8]=cv;
      }
      float a = A.fc1b[c];
      #pragma unroll
      for (int j=0;j<16;++j) a += te[j]*A.fc1W[j*64+c];
      sm.pre.tb0[r*64+c] = a*sigmoidf_(a);
      __syncthreads();
      float b2v = A.fc2b[c];
      #pragma unroll 8
      for (int k=0;k<64;++k) b2v += sm.pre.tb0[r*64+k]*A.fc2W[k*64+c];
      sm.pre.tb1[r*64+c] = b2v;
      __syncthreads();
      float hti = A.tprojb[c];
      #pragma unroll 8
      for (int k=0;k<64;++k) hti += sm.pre.tb1[r*64+k]*A.tprojW[k*64+c];
      A.htime[row*64+c] = hti;
    }
  }
  {
    // GEMM1 partial: rowgroup rg = b>>1 (16 rows), K-half kq = b&1 (2048 k), 8 chunks of 256
    const int rg = b>>1, kq = b&1;
    const int rows0 = rg*16, k0 = kq*2048;
    const int col4 = (t&15)*4;
    const int rq4  = ((t>>4)&3)*4;
    const int ksub = (t>>6)*64;

    float4 a0={0,0,0,0}, a1={0,0,0,0}, a2={0,0,0,0}, a3={0,0,0,0};

    for (int ch=0; ch<8; ++ch){
      __syncthreads();
      #pragma unroll
      for (int i=0;i<4;++i){
        int fi = t + 256*i;
        int xr = fi>>6, kk = (fi&63)<<2;
        *(float4*)&sm.pre.xs[xr*260+kk] =
            *(const float4*)&A.x[(size_t)(rows0+xr)*4096 + k0 + ch*256 + kk];
      }
      __syncthreads();
      const float* wp = &A.nodeW[(size_t)(k0 + ch*256 + ksub)*64 + col4];
      const float* xp = &sm.pre.xs[rq4*260 + ksub];
      #pragma unroll 8
      for (int kk=0; kk<64; ++kk){
        float4 w  = *(const float4*)&wp[kk*64];
        float x0 = xp[kk];
        float x1 = xp[260+kk];
        float x2 = xp[520+kk];
        float x3 = xp[780+kk];
        a0.x += x0*w.x; a0.y += x0*w.y; a0.z += x0*w.z; a0.w += x0*w.w;
        a1.x += x1*w.x; a1.y += x1*w.y; a1.z += x1*w.z; a1.w += x1*w.w;
        a2.x += x2*w.x; a2.y += x2*w.y; a2.z += x2*w.z; a2.w += x2*w.w;
        a3.x += x3*w.x; a3.y += x3*w.y; a3.z += x3*w.z; a3.w += x3*w.w;
      }
    }
    __syncthreads();
    {
      const int kqi = t>>6;
      *(float4*)&sm.pre.xs[(kqi*16 + rq4 + 0)*64 + col4] = a0;
      *(float4*)&sm.pre.xs[(kqi*16 + rq4 + 1)*64 + col4] = a1;
      *(float4*)&sm.pre.xs[(kqi*16 + rq4 + 2)*64 + col4] = a2;
      *(float4*)&sm.pre.xs[(kqi*16 + rq4 + 3)*64 + col4] = a3;
    }
    __syncthreads();
    {
      const int row = t>>4, c4 = (t&15)*4;
      float4 s = {0,0,0,0};
      #pragma unroll
      for (int q=0;q<4;++q){
        float4 v = *(const float4*)&sm.pre.xs[(q*16+row)*64 + c4];
        s.x+=v.x; s.y+=v.y; s.z+=v.z; s.w+=v.w;
      }
      *(float4*)&A.h0p[(size_t)kq*(NB*HDM) + (rows0+row)*64 + c4] = s;
    }
  }
  gsync(A.bar + (slot++));   // all GEMM1 partials + zeroing visible

  // ================= Phase assemble: 8 rows/block, 4 rows per pass =================
  {
    const int r = t>>6, c = t&63;
    for (int pass=0; pass<2; ++pass){
      if (pass) __syncthreads();
      const int row = b*8 + pass*4 + r;
      if (pass==0 && r==0){
        float pl[16];
        #pragma unroll
        for (int j=0;j<16;++j){
          float a = A.pelb[j];
          for (int w=0;w<20;++w) a += A.penb[w]*A.pelW[w*16+j];
          pl[j]=a;
        }
        float a = A.catb[c];
        #pragma unroll
        for (int j=0;j<16;++j) a += pl[j]*A.catW[(64+j)*64+c];
        sm.as.cvec[c]=a;
      }
      float h0 = A.nodeb[c];
      #pragma unroll
      for (int q=0;q<2;++q) h0 += A.h0p[(size_t)q*(NB*HDM) + row*64 + c];
      sm.as.sa[t] = h0;
      sm.as.sb[t] = A.htime[row*64+c];
      __syncthreads();
      float a = A.tcatb[c];
      #pragma unroll 4
      for (int k=0;k<64;++k){
        a += sm.as.sa[r*64+k]*A.tcatW[k*64+c];
        a += sm.as.sb[r*64+k]*A.tcatW[(64+k)*64+c];
      }
      __syncthreads();
      sm.as.sa[t] = a;
      __syncthreads();
      float hv = sm.as.cvec[c];
      #pragma unroll 8
      for (int k=0;k<64;++k) hv += sm.as.sa[r*64+k]*A.catW[k*64+c];
      A.hbuf[row*64+c] = hv;
    }
  }
  // no grid sync needed: layer-0 phase A reads only this block's own 8 rows of hbuf

  // ================= layers =================
  for (int l=0; l<NLAY; ++l){
    const float* bnaccPrev = (l==0) ? A.bnacc : A.bnacc + (l-1)*384;
    const float* gPrev = (l==0) ? A.bng : A.bng + (l-1)*192 + 128;
    const float* bPrev = (l==0) ? A.bnb : A.bnb + (l-1)*192 + 128;
    const float* Whh = A.gruWhh + l*12288;
    const float* bhh = A.grubhh + l*192;
    const float* Wq  = A.Wqkv + l*12288;
    const float* bqv = A.bqkv + l*192;
    float* hsumL  = A.hsum + l*64;
    float* bnaccL = A.bnacc + l*384;

    // ---- Phase A: [bn3 prev] + hsum + gh + bf16 QKV packs (8 rows, legacy body) ----
    __syncthreads();   // protect LDS union reuse vs preceding phase
    {
      const int row0 = b*8;
      #pragma unroll
      for (int i=0;i<2;++i){
        int idx = t + 256*i;
        int rl = idx>>6, c = idx&63;
        int row = row0 + rl;
        float hv;
        if (l==0){
          hv = A.hbuf[row*64+c];
        } else {
          float mu = bnaccPrev[256+c]*(1.f/NB);
          float va = bnaccPrev[320+c]*(1.f/NB) - mu*mu;
          hv = gPrev[c]*(A.smlp[row*64+c]-mu)*rsqrtf(va+1e-5f)+bPrev[c];
          A.hbuf[row*64+c] = hv;
        }
        sm.a.sa[idx] = hv;
      }
      __syncthreads();
      if (t<64){
        float s = 0.f;
        #pragma unroll
        for (int rl=0;rl<8;++rl) s += sm.a.sa[rl*64+t];
        atomicAdd(&hsumL[t], s);
      }
      if (t < 192){
        const int cc = t;
        float ag[8], aq[8];
        float bh = bhh[cc], bq_ = bqv[cc];
        #pragma unroll
        for (int rl=0;rl<8;++rl){ ag[rl]=bh; aq[rl]=bq_; }
        #pragma unroll 4
        for (int k=0;k<64;++k){
          float wh = Whh[k*192+cc];
          float wq = Wq [k*192+cc];
          #pragma unroll
          for (int rl=0;rl<8;++rl){
            float hk = sm.a.sa[rl*64+k];
            ag[rl] += hk*wh;
            aq[rl] += hk*wq;
          }
        }
        #pragma unroll
        for (int rl=0;rl<8;++rl){
          int rw = row0 + rl;
          A.gh[(size_t)rw*192+cc] = ag[rl];
          float aqv = aq[rl];
          if (cc < 64){
            int hd = cc>>4, dh = cc&15;
            size_t base = ((size_t)(hd<<11) + rw)*32;
            A.Qb[base+dh] = f2b_rne(aqv*0.25f);
            A.Qb[base+16+dh] = 0;
          } else if (cc < 128){
            int c2 = cc-64, hd = c2>>4, dh = c2&15;
            size_t base = ((size_t)(hd<<11) + rw)*32;
            A.Kb[base+dh] = f2b_rne(aqv);
            A.Kb[base+16+dh] = 0;
          } else {
            int c2 = cc-128, hd = c2>>4, dh = c2&15;
            A.Vt[((size_t)(hd*16+dh))*2048 + rw] = f2b_rne(aqv);
          }
        }
      }
    }
    gsync(A.bar + (slot++));   // QKV complete

    // ---- Phase attn: 2 units/block: (qt = b&127, head = (b>>7) + 2*it) ----
    for (int it=0; it<2; ++it){
      if (it) __syncthreads();   // protect Pl/Os/ms/ls reuse across units
      const int w = t>>6, lane = t&63;
      const int q15 = lane & 15, quad = lane >> 4;
      const int qt = b & 127, head = (b>>7) + 2*it;
      const int qrow = qt*16 + q15;
      const int key00 = w*512;
      unsigned short* Plw = &sm.at.Pl[w*640];

      const bf16x8 qf = *(const bf16x8*)&A.Qb[(((size_t)(head<<11))+qrow)*32 + quad*8];
      const unsigned short* Kb_h = A.Kb + ((size_t)(head<<11))*32;
      const unsigned short* Vrow = A.Vt + ((size_t)(head*16+q15))*2048;

      v4f O = {0.f,0.f,0.f,0.f};
      float m = -1e30f, lsum = 0.f;

      bf16x8 kf0 = *(const bf16x8*)&Kb_h[(size_t)(key00 + q15)*32 + quad*8];
      bf16x8 kf1 = *(const bf16x8*)&Kb_h[(size_t)(key00 + 16 + q15)*32 + quad*8];
      bf16x8 vf  = *(const bf16x8*)&Vrow[key00 + quad*8];

      for (int c=0; c<16; ++c){
        bf16x8 nk0, nk1, nv;
        if (c < 15){
          int nk = key00 + (c+1)*32;
          nk0 = *(const bf16x8*)&Kb_h[(size_t)(nk + q15)*32 + quad*8];
          nk1 = *(const bf16x8*)&Kb_h[(size_t)(nk + 16 + q15)*32 + quad*8];
          nv  = *(const bf16x8*)&Vrow[nk + quad*8];
        }
        v4f z = {0.f,0.f,0.f,0.f};
        v4f s0 = __builtin_amdgcn_mfma_f32_16x16x32_bf16(kf0, qf, z, 0,0,0);
        v4f s1 = __builtin_amdgcn_mfma_f32_16x16x32_bf16(kf1, qf, z, 0,0,0);
        float cmax = fmaxf(fmaxf(fmaxf(s0[0],s0[1]),fmaxf(s0[2],s0[3])),
                           fmaxf(fmaxf(s1[0],s1[1]),fmaxf(s1[2],s1[3])));
        cmax = fmaxf(cmax, __shfl_xor(cmax,16,64));
        cmax = fmaxf(cmax, __shfl_xor(cmax,32,64));
        float mnew = fmaxf(m, cmax);
        float alpha = __expf(m - mnew);
        float p0=__expf(s0[0]-mnew), p1=__expf(s0[1]-mnew), p2=__expf(s0[2]-mnew), p3=__expf(s0[3]-mnew);
        float p4=__expf(s1[0]-mnew), p5=__expf(s1[1]-mnew), p6=__expf(s1[2]-mnew), p7=__expf(s1[3]-mnew);
        lsum = alpha*lsum + ((p0+p1)+(p2+p3)+((p4+p5)+(p6+p7)));
        m = mnew;
        O[0]*=alpha; O[1]*=alpha; O[2]*=alpha; O[3]*=alpha;
        *(uint2*)&Plw[q15*40 + quad*4]      = make_uint2(pk2(p0,p1), pk2(p2,p3));
        *(uint2*)&Plw[q15*40 + 16 + quad*4] = make_uint2(pk2(p4,p5), pk2(p6,p7));
        asm volatile("s_waitcnt lgkmcnt(0)" ::: "memory");
        bf16x8 pf = *(const bf16x8*)&Plw[q15*40 + quad*8];
        O = __builtin_amdgcn_mfma_f32_16x16x32_bf16(vf, pf, O, 0,0,0);
        kf0 = nk0; kf1 = nk1; vf = nv;
      }
      lsum += __shfl_xor(lsum,16,64);
      lsum += __shfl_xor(lsum,32,64);
      #pragma unroll
      for (int j=0;j<4;++j) sm.at.Os[w*272 + q15*17 + quad*4 + j] = O[j];
      if (quad==0){ sm.at.ms[w*16+q15]=m; sm.at.ls[w*16+q15]=lsum; }
      __syncthreads();
      {
        const int dh = t&15, q = t>>4;
        float m0=sm.at.ms[q], m1=sm.at.ms[16+q], m2=sm.at.ms[32+q], m3=sm.at.ms[48+q];
        float mm = fmaxf(fmaxf(m0,m1),fmaxf(m2,m3));
        float a0=__expf(m0-mm), a1=__expf(m1-mm), a2=__expf(m2-mm), a3=__expf(m3-mm);
        float ll = a0*sm.at.ls[q]+a1*sm.at.ls[16+q]+a2*sm.at.ls[32+q]+a3*sm.at.ls[48+q];
        float oo = a0*sm.at.Os[q*17+dh] + a1*sm.at.Os[272+q*17+dh]
                 + a2*sm.at.Os[544+q*17+dh] + a3*sm.at.Os[816+q*17+dh];
        A.o_out[(size_t)(qt*16+q)*64 + head*16 + dh] = oo / ll;
      }
    }
    gsync(A.bar + (slot++));   // o_out complete

    // ---- Phase B2: o-proj + GRU + bn1/bn2 stats (8 rows, legacy body) ----
    {
      const float* Wg  = A.convWg + l*4096;
      const float* Wih = A.gruWih + l*12288;
      const float* bih = A.grubih + l*192;
      const float* WoL = A.Wo + l*4096;
      const float* boL = A.bo + l*64;
      const int row0 = b*8;

      if (t<64){
        float a=0.f;
        #pragma unroll 8
        for (int k=0;k<64;++k) a += hsumL[k]*Wg[k*64+t];
        sm.b2.smv[t]=a;
      }
      #pragma unroll
      for (int i=0;i<2;++i){
        int idx = t + 256*i;
        int rl = idx>>6, c = idx&63;
        sm.b2.sa[idx] = A.hbuf[(size_t)(row0+rl)*64+c];
        sm.b2.os[idx] = A.o_out[(size_t)(row0+rl)*64+c];
      }
      __syncthreads();
      if (t<192){
        float a = bih[t];
        #pragma unroll 8
        for (int k=0;k<64;++k) a += sm.b2.smv[k]*Wih[k*192+t];
        sm.b2.sgi[t]=a;
      }
      __syncthreads();

      {
        const int c = t&63, rg = t>>6;   // rows 2rg, 2rg+1
        float o2a = boL[c], o2b = boL[c];
        #pragma unroll 4
        for (int k=0;k<64;++k){
          float w = WoL[k*64+c];
          o2a += sm.b2.os[(rg*2  )*64+k]*w;
          o2b += sm.b2.os[(rg*2+1)*64+k]*w;
        }
        #pragma unroll
        for (int i=0;i<2;++i){
          int rl = rg*2 + i;
          int row = row0 + rl;
          float o2 = i ? o2b : o2a;
          float hv = sm.b2.sa[rl*64+c];
          float s2v = o2 + hv;
          float ir = sm.b2.sgi[c]      + A.gh[(size_t)row*192+c];
          float iz = sm.b2.sgi[64+c]   + A.gh[(size_t)row*192+64+c];
          float inn = sm.b2.sgi[128+c];
          float hn  = A.gh[(size_t)row*192+128+c];
          float rr_ = sigmoidf_(ir);
          float zz  = sigmoidf_(iz);
          float nn  = tanhfast_(inn + rr_*hn);
          float s1v = (1.f-zz)*nn + zz*hv + hv;   // hc + h
          A.s1[(size_t)row*64+c] = s1v;
          A.s2[(size_t)row*64+c] = s2v;
          sm.b2.Sb1[rl*64+c] = s1v;
          sm.b2.Sb2[rl*64+c] = s2v;
        }
      }
      __syncthreads();
      if (t<64){
        float a=0.f,aq=0.f,bb=0.f,bq2=0.f;
        #pragma unroll
        for (int rl=0;rl<8;++rl){
          float v1 = sm.b2.Sb1[rl*64+t], v2 = sm.b2.Sb2[rl*64+t];
          a+=v1; aq+=v1*v1; bb+=v2; bq2+=v2*v2;
        }
        atomicAdd(&bnaccL[t],a);     atomicAdd(&bnaccL[64+t],aq);
        atomicAdd(&bnaccL[128+t],bb); atomicAdd(&bnaccL[192+t],bq2);
      }
    }
    gsync(A.bar + (slot++));   // bn1/bn2 stats complete

    // ---- Phase C: bn1/bn2 apply + MLP + bn3 stats (8 rows, legacy body) ----
    {
      const float* bngL = A.bng + l*192;
      const float* bnbL = A.bnb + l*192;
      const float* W1l = A.W1 + l*8192;
      const float* b1l = A.b1 + l*128;
      const float* W2l = A.W2 + l*8192;
      const float* b2l = A.b2 + l*64;
      const int row0 = b*8;

      #pragma unroll
      for (int i=0;i<2;++i){
        int idx = t + 256*i;
        int rl = idx>>6, c = idx&63;
        int row = row0 + rl;
        float mu1 = bnaccL[c]*(1.f/NB);
        float va1 = bnaccL[64+c]*(1.f/NB) - mu1*mu1;
        float mu2 = bnaccL[128+c]*(1.f/NB);
        float va2 = bnaccL[192+c]*(1.f/NB) - mu2*mu2;
        float h1 = bngL[c]*(A.s1[(size_t)row*64+c]-mu1)*rsqrtf(va1+1e-5f)+bnbL[c];
        float h2 = bngL[64+c]*(A.s2[(size_t)row*64+c]-mu2)*rsqrtf(va2+1e-5f)+bnbL[64+c];
        sm.c.sa[idx] = h1+h2;
      }
      __syncthreads();
      {
        const int hj = t&127, rgq = t>>7;   // rows rgq*4 .. +3
        float a0v=b1l[hj], a1v=b1l[hj], a2v=b1l[hj], a3v=b1l[hj];
        #pragma unroll 4
        for (int k=0;k<64;++k){
          float w = W1l[k*128+hj];
          a0v += sm.c.sa[(rgq*4  )*64+k]*w;
          a1v += sm.c.sa[(rgq*4+1)*64+k]*w;
          a2v += sm.c.sa[(rgq*4+2)*64+k]*w;
          a3v += sm.c.sa[(rgq*4+3)*64+k]*w;
        }
        sm.c.sh[(rgq*4  )*128+hj] = fmaxf(a0v,0.f);
        sm.c.sh[(rgq*4+1)*128+hj] = fmaxf(a1v,0.f);
        sm.c.sh[(rgq*4+2)*128+hj] = fmaxf(a2v,0.f);
        sm.c.sh[(rgq*4+3)*128+hj] = fmaxf(a3v,0.f);
      }
      __syncthreads();
      {
        const int c = t&63, rg = t>>6;   // rows 2rg, 2rg+1
        float moa = b2l[c], mob = b2l[c];
        #pragma unroll 4
        for (int k=0;k<128;++k){
          float w = W2l[k*64+c];
          moa += sm.c.sh[(rg*2  )*128+k]*w;
          mob += sm.c.sh[(rg*2+1)*128+k]*w;
        }
        #pragma unroll
        for (int i=0;i<2;++i){
          int rl = rg*2+i;
          float smv2 = sm.c.sa[rl*64+c] + (i ? mob : moa);
          A.smlp[(size_t)(row0+rl)*64+c] = smv2;
          sm.c.S2[rl*64+c] = smv2;
        }
      }
      __syncthreads();
      if (t<64){
        float a=0.f,aq=0.f;
        #pragma unroll
        for (int rl=0;rl<8;++rl){ float v=sm.c.S2[rl*64+t]; a+=v; aq+=v*v; }
        atomicAdd(&bnaccL[256+t],a); atomicAdd(&bnaccL[320+t],aq);
      }
    }
    gsync(A.bar + (slot++));   // bn3 stats + smlp complete
  }

  // ================= Phase out: GEMM2 + fused final bn3, 2 units/block =================
  {
    const float* bnacc4 = A.bnacc + 4*384;
    const float* g4 = A.bng + 896;
    const float* b4 = A.bnb + 896;
    for (int it=0; it<2; ++it){
      if (it) __syncthreads();   // protect hsT reuse across units
      const int u = b + NBLK*it;
      const int rg = u>>2, cg = u&3;
      const int rows0 = rg*16;
      #pragma unroll
      for (int i=0;i<4;++i){
        int idx = t + 256*i;
        int k = idx&63, rr = idx>>6;
        float mu = bnacc4[256+k]*(1.f/NB);
        float va = bnacc4[320+k]*(1.f/NB)-mu*mu;
        sm.o.hsT[k*20+rr] = g4[k]*(A.smlp[(size_t)(rows0+rr)*64+k]-mu)*rsqrtf(va+1e-5f)+b4[k];
      }
      __syncthreads();
      const int cc = cg*1024 + t*4;
      float4 acc[16];
      {
        float4 bv = *(const float4*)&A.outb[cc];
        #pragma unroll
        for (int rr=0;rr<16;++rr) acc[rr]=bv;
      }
      #pragma unroll 4
      for (int k=0;k<64;++k){
        float4 w = *(const float4*)&A.outW[(size_t)k*4096+cc];
        const float4* hp = (const float4*)&sm.o.hsT[k*20];
        float4 h0=hp[0], h1=hp[1], h2=hp[2], h3=hp[3];
        acc[0].x+=h0.x*w.x;  acc[0].y+=h0.x*w.y;  acc[0].z+=h0.x*w.z;  acc[0].w+=h0.x*w.w;
        acc[1].x+=h0.y*w.x;  acc[1].y+=h0.y*w.y;  acc[1].z+=h0.y*w.z;  acc[1].w+=h0.y*w.w;
        acc[2].x+=h0.z*w.x;  acc[2].y+=h0.z*w.y;  acc[2].z+=h0.z*w.z;  acc[2].w+=h0.z*w.w;
        acc[3].x+=h0.w*w.x;  acc[3].y+=h0.w*w.y;  acc[3].z+=h0.w*w.z;  acc[3].w+=h0.w*w.w;
        acc[4].x+=h1.x*w.x;  acc[4].y+=h1.x*w.y;  acc[4].z+=h1.x*w.z;  acc[4].w+=h1.x*w.w;
        acc[5].x+=h1.y*w.x;  acc[5].y+=h1.y*w.y;  acc[5].z+=h1.y*w.z;  acc[5].w+=h1.y*w.w;
        acc[6].x+=h1.z*w.x;  acc[6].y+=h1.z*w.y;  acc[6].z+=h1.z*w.z;  acc[6].w+=h1.z*w.w;
        acc[7].x+=h1.w*w.x;  acc[7].y+=h1.w*w.y;  acc[7].z+=h1.w*w.z;  acc[7].w+=h1.w*w.w;
        acc[8].x+=h2.x*w.x;  acc[8].y+=h2.x*w.y;  acc[8].z+=h2.x*w.z;  acc[8].w+=h2.x*w.w;
        acc[9].x+=h2.y*w.x;  acc[9].y+=h2.y*w.y;  acc[9].z+=h2.y*w.z;  acc[9].w+=h2.y*w.w;
        acc[10].x+=h2.z*w.x; acc[10].y+=h2.z*w.y; acc[10].z+=h2.z*w.z; acc[10].w+=h2.z*w.w;
        acc[11].x+=h2.w*w.x; acc[11].y+=h2.w*w.y; acc[11].z+=h2.w*w.z; acc[11].w+=h2.w*w.w;
        acc[12].x+=h3.x*w.x; acc[12].y+=h3.x*w.y; acc[12].z+=h3.x*w.z; acc[12].w+=h3.x*w.w;
        acc[13].x+=h3.y*w.x; acc[13].y+=h3.y*w.y; acc[13].z+=h3.y*w.z; acc[13].w+=h3.y*w.w;
        acc[14].x+=h3.z*w.x; acc[14].y+=h3.z*w.y; acc[14].z+=h3.z*w.z; acc[14].w+=h3.z*w.w;
        acc[15].x+=h3.w*w.x; acc[15].y+=h3.w*w.y; acc[15].z+=h3.w*w.z; acc[15].w+=h3.w*w.w;
      }
      #pragma unroll
      for (int rr=0;rr<16;++rr)
        *(float4*)&A.out[(size_t)(rows0+rr)*4096+cc] = acc[rr];
    }
  }
}

// ============================ host ============================

extern "C" void kernel_launch(void* const* d_in, const int* in_sizes, int n_in,
                              void* d_out, int out_size, void* d_ws, size_t ws_size,
                              hipStream_t stream)
{
  (void)in_sizes; (void)n_in; (void)out_size; (void)ws_size;
  KArgs A;
  A.x      = (const float*)d_in[0];
  A.tt     = (const float*)d_in[1];
  A.freqs  = (const float*)d_in[2];
  A.fc1W   = (const float*)d_in[3];
  A.fc1b   = (const float*)d_in[4];
  A.fc2W   = (const float*)d_in[5];
  A.fc2b   = (const float*)d_in[6];
  A.nodeW  = (const float*)d_in[7];
  A.nodeb  = (const float*)d_in[8];
  A.tprojW = (const float*)d_in[9];
  A.tprojb = (const float*)d_in[10];
  A.tcatW  = (const float*)d_in[11];
  A.tcatb  = (const float*)d_in[12];
  A.penb   = (const float*)d_in[14];
  A.pelW   = (const float*)d_in[15];
  A.pelb   = (const float*)d_in[16];
  A.catW   = (const float*)d_in[17];
  A.catb   = (const float*)d_in[18];
  A.convWg = (const float*)d_in[19];
  A.gruWih = (const float*)d_in[20];
  A.grubih = (const float*)d_in[21];
  A.gruWhh = (const float*)d_in[22];
  A.grubhh = (const float*)d_in[23];
  A.Wqkv   = (const float*)d_in[24];
  A.bqkv   = (const float*)d_in[25];
  A.Wo     = (const float*)d_in[26];
  A.bo     = (const float*)d_in[27];
  A.bng    = (const float*)d_in[28];
  A.bnb    = (const float*)d_in[29];
  A.W1     = (const float*)d_in[30];
  A.b1     = (const float*)d_in[31];
  A.W2     = (const float*)d_in[32];
  A.b2     = (const float*)d_in[33];
  A.outW   = (const float*)d_in[34];
  A.outb   = (const float*)d_in[35];

  float* ws = (float*)d_ws;
  A.htime = ws;                      // 131072
  A.hbuf  = A.htime + 131072;        // 131072
  A.gh    = A.hbuf + 131072;         // 393216
  A.s1    = A.gh + 393216;           // 131072
  A.s2    = A.s1 + 131072;           // 131072
  A.smlp  = A.s2 + 131072;           // 131072
  A.o_out = A.smlp + 131072;         // 131072
  A.hsum  = A.o_out + 131072;        // 320
  A.bnacc = A.hsum + 320;            // 1920
  A.Qb = (unsigned short*)(A.bnacc + 1920);   // 262144 ushort
  A.Kb = A.Qb + 262144;                       // 262144 ushort
  A.Vt = A.Kb + 262144;                       // 65536 ushort
  A.h0p  = (float*)(A.Vt + 65536);   // fused path uses only slots 0..1 (2*131072)
  A.bar  = (unsigned*)(A.h0p + 2*(NB*HDM));   // 64 u32 barrier slots, inside proven ws
  A.out  = (float*)d_out;

  hipMemsetAsync(A.bar, 0, 64*sizeof(unsigned), stream);
  k_fused<<<dim3(NBLK), dim3(256), 0, stream>>>(A);
}